// Round 1
// baseline (78.788 us; speedup 1.0000x reference)
//
#include <hip/hip_runtime.h>
#include <hip/hip_bf16.h>
#include <stdint.h>

typedef short bf16x8 __attribute__((ext_vector_type(8)));
typedef float f32x4  __attribute__((ext_vector_type(4)));

#define B_   32
#define CIN  32
#define COUT 64
#define H_   128
#define W_   128
#define PH   130
#define PW   130
#define HW   (H_ * W_)

static __device__ __forceinline__ ushort f2bf(float v) {
    union { float f; uint32_t u; } cv; cv.f = v;
    uint32_t u = cv.u;
    // round-to-nearest-even bf16
    uint32_t r = (u + 0x7FFFu + ((u >> 16) & 1u)) >> 16;
    return (ushort)r;
}

// ---------------------------------------------------------------------------
// Prep 1: fp32 NCHW input -> bf16 NHWC with physical zero padding
// P[b][y][x][cin], y,x in [0,130); interior (1..128) holds input, border = 0
// ---------------------------------------------------------------------------
__global__ void prep_input_kernel(const float* __restrict__ in, ushort* __restrict__ P) {
    int idx = blockIdx.x * blockDim.x + threadIdx.x;
    if (idx >= B_ * PH * PW) return;
    int x = idx % PW;
    int t = idx / PW;
    int y = t % PH;
    int b = t / PH;

    bf16x8 v[4];
    if (x >= 1 && x <= W_ && y >= 1 && y <= H_) {
        const float* src = in + (size_t)b * CIN * HW + (size_t)(y - 1) * W_ + (x - 1);
#pragma unroll
        for (int k = 0; k < 4; ++k)
#pragma unroll
            for (int j = 0; j < 8; ++j)
                v[k][j] = (short)f2bf(src[(size_t)(k * 8 + j) * HW]);
    } else {
#pragma unroll
        for (int k = 0; k < 4; ++k)
#pragma unroll
            for (int j = 0; j < 8; ++j)
                v[k][j] = 0;
    }
    bf16x8* dst = (bf16x8*)(P + (size_t)idx * CIN);
#pragma unroll
    for (int k = 0; k < 4; ++k) dst[k] = v[k];
}

// ---------------------------------------------------------------------------
// Prep 2: pack weights [Cout][Cin][3][3] fp32 -> bf16 A-fragment order
// Wp[tap][ocg][lane][j] = W[ocg*16 + (lane&15)][8*(lane>>4)+j][ky][kx]
// ---------------------------------------------------------------------------
__global__ void prep_w_kernel(const float* __restrict__ wt, ushort* __restrict__ Wp) {
    int p = blockIdx.x * blockDim.x + threadIdx.x;
    if (p >= COUT * CIN * 9) return;  // 18432
    int j    = p & 7;
    int lane = (p >> 3) & 63;
    int g    = (p >> 9) & 3;
    int tap  = p >> 11;          // 0..8
    int oc   = g * 16 + (lane & 15);
    int cin  = (lane >> 4) * 8 + j;
    int ky   = tap / 3;
    int kx   = tap % 3;
    float v = wt[(((size_t)oc * CIN + cin) * 3 + ky) * 3 + kx];
    Wp[p] = f2bf(v);
}

// ---------------------------------------------------------------------------
// Main: implicit GEMM, tap-outer. Block = 4 waves = one (b,h) output row.
// Wave: M=64 (all oc), N=32 pixels, 9 taps -> 72 MFMAs. No LDS.
// ---------------------------------------------------------------------------
__global__ __launch_bounds__(256, 4) void conv_mfma_kernel(
    const ushort* __restrict__ P, const ushort* __restrict__ Wp,
    float* __restrict__ out) {
    int blk  = blockIdx.x;
    int b    = blk >> 7;       // /128
    int h    = blk & 127;
    int tid  = threadIdx.x;
    int wid  = tid >> 6;
    int lane = tid & 63;
    int w0   = wid * 32;
    int lhi  = lane >> 4;      // 0..3
    int llo  = lane & 15;

    f32x4 acc[4][2];
#pragma unroll
    for (int g = 0; g < 4; ++g)
#pragma unroll
        for (int n = 0; n < 2; ++n) {
            acc[g][n][0] = 0.f; acc[g][n][1] = 0.f;
            acc[g][n][2] = 0.f; acc[g][n][3] = 0.f;
        }

    const ushort* pb = P + (size_t)b * PH * PW * CIN;

#pragma unroll
    for (int tap = 0; tap < 9; ++tap) {
        int dy = tap / 3;   // 0..2  (input row h+dy-1 lives at padded row h+dy)
        int dx = tap % 3;
        const ushort* prow =
            pb + ((size_t)(h + dy) * PW + (w0 + llo + dx)) * CIN + lhi * 8;
        bf16x8 Bf0 = *(const bf16x8*)(prow);
        bf16x8 Bf1 = *(const bf16x8*)(prow + 16 * CIN);
#pragma unroll
        for (int g = 0; g < 4; ++g) {
            bf16x8 Af = *(const bf16x8*)(Wp + ((size_t)(tap * 4 + g) * 64 + lane) * 8);
            acc[g][0] = __builtin_amdgcn_mfma_f32_16x16x32_bf16(Af, Bf0, acc[g][0], 0, 0, 0);
            acc[g][1] = __builtin_amdgcn_mfma_f32_16x16x32_bf16(Af, Bf1, acc[g][1], 0, 0, 0);
        }
    }

    // Store: C/D layout col=lane&15 (pixel), row=(lane>>4)*4+r (oc within ocg)
    float* obase = out + (size_t)b * COUT * HW + (size_t)h * W_;
#pragma unroll
    for (int g = 0; g < 4; ++g)
#pragma unroll
        for (int nf = 0; nf < 2; ++nf) {
            int w = w0 + nf * 16 + llo;
#pragma unroll
            for (int r = 0; r < 4; ++r) {
                int oc = g * 16 + lhi * 4 + r;
                obase[(size_t)oc * HW + w] = acc[g][nf][r];
            }
        }
}

// ---------------------------------------------------------------------------
// Fallback: naive fp32 direct conv (only if workspace is too small)
// ---------------------------------------------------------------------------
__global__ void conv_naive_kernel(const float* __restrict__ in,
                                  const float* __restrict__ wt,
                                  float* __restrict__ out) {
    int idx = blockIdx.x * blockDim.x + threadIdx.x;
    if (idx >= B_ * COUT * HW) return;
    int w  = idx & 127;
    int h  = (idx >> 7) & 127;
    int oc = (idx >> 14) & 63;
    int b  = idx >> 20;
    float s = 0.f;
    for (int c = 0; c < CIN; ++c)
        for (int ky = 0; ky < 3; ++ky) {
            int y = h + ky - 1;
            if ((unsigned)y >= (unsigned)H_) continue;
            for (int kx = 0; kx < 3; ++kx) {
                int x = w + kx - 1;
                if ((unsigned)x >= (unsigned)W_) continue;
                s += in[((size_t)(b * CIN + c) * H_ + y) * W_ + x] *
                     wt[(((size_t)oc * CIN + c) * 3 + ky) * 3 + kx];
            }
        }
    out[idx] = s;
}

extern "C" void kernel_launch(void* const* d_in, const int* in_sizes, int n_in,
                              void* d_out, int out_size, void* d_ws, size_t ws_size,
                              hipStream_t stream) {
    const float* in = (const float*)d_in[0];
    const float* wt = (const float*)d_in[1];
    float* out = (float*)d_out;

    size_t P_bytes  = (size_t)B_ * PH * PW * CIN * 2;       // 34,611,200
    size_t Wp_bytes = (size_t)COUT * CIN * 9 * 2;           // 36,864
    size_t need = P_bytes + Wp_bytes;

    if (ws_size >= need) {
        ushort* P  = (ushort*)d_ws;
        ushort* Wp = (ushort*)((char*)d_ws + P_bytes);
        int n1 = B_ * PH * PW;
        prep_input_kernel<<<(n1 + 255) / 256, 256, 0, stream>>>(in, P);
        prep_w_kernel<<<(COUT * CIN * 9 + 255) / 256, 256, 0, stream>>>(wt, Wp);
        conv_mfma_kernel<<<B_ * H_, 256, 0, stream>>>(P, Wp, out);
    } else {
        int total = B_ * COUT * HW;
        conv_naive_kernel<<<(total + 255) / 256, 256, 0, stream>>>(in, wt, out);
    }
}

// Round 2
// 52.578 us; speedup vs baseline: 1.4985x; 1.4985x over previous
//
#include <hip/hip_runtime.h>
#include <hip/hip_bf16.h>
#include <stdint.h>

typedef short bf16x8 __attribute__((ext_vector_type(8)));
typedef float f32x4  __attribute__((ext_vector_type(4)));

#define B_   32
#define CIN  32
#define COUT 64
#define H_   128
#define W_   128
#define HW   (H_ * W_)
#define T_   4            // output rows per block
#define RROWS 6           // staged input rows = T_+2
#define PXW  130          // padded width

static __device__ __forceinline__ ushort f2bf(float v) {
    union { float f; uint32_t u; } cv; cv.f = v;
    uint32_t u = cv.u;
    uint32_t r = (u + 0x7FFFu + ((u >> 16) & 1u)) >> 16;   // RNE
    return (ushort)r;
}

// ---------------------------------------------------------------------------
// Weight pack: [Cout][Cin][3][3] fp32 -> bf16 A-fragment order
// Wp[tap][ocg][lane][j] = W[ocg*16 + (lane&15)][8*(lane>>4)+j][ky][kx]
// ---------------------------------------------------------------------------
__global__ void prep_w_kernel(const float* __restrict__ wt, ushort* __restrict__ Wp) {
    int p = blockIdx.x * blockDim.x + threadIdx.x;
    if (p >= COUT * CIN * 9) return;  // 18432
    int j    = p & 7;
    int lane = (p >> 3) & 63;
    int g    = (p >> 9) & 3;
    int tap  = p >> 11;
    int oc   = g * 16 + (lane & 15);
    int cin  = (lane >> 4) * 8 + j;
    int ky   = tap / 3;
    int kx   = tap % 3;
    Wp[p] = f2bf(wt[(((size_t)oc * CIN + cin) * 3 + ky) * 3 + kx]);
}

// ---------------------------------------------------------------------------
// Fused: stage 6 padded rows (NCHW fp32 -> bf16 NHWC in LDS, XOR-swizzled),
// then implicit-GEMM. Block = (b, 4 rows), 4 waves, wave = one output row.
// LDS col (r,px) = 64 B of 32 ch; 16B slot q stored at q ^ ((px>>1)&3).
// ---------------------------------------------------------------------------
__global__ __launch_bounds__(256, 2) void conv_fused_kernel(
    const float* __restrict__ in, const ushort* __restrict__ Wp,
    float* __restrict__ out) {
    __shared__ ushort lds[RROWS * PXW * 32];   // 49,920 B

    int blk = blockIdx.x;
    int b   = blk >> 5;            // /32
    int h0  = (blk & 31) * T_;
    int tid = threadIdx.x;

    // ---- stage: thread = one (row, px) column, loop 32 channels ----
    for (int i = tid; i < RROWS * PXW; i += 256) {
        int r  = i / PXW;
        int px = i - r * PXW;
        int gy = h0 + r - 1;
        bf16x8 v[4];
        if (gy >= 0 && gy < H_ && px >= 1 && px <= W_) {
            const float* src = in + ((size_t)b * CIN * H_ + gy) * W_ + (px - 1);
#pragma unroll
            for (int q = 0; q < 4; ++q)
#pragma unroll
                for (int j = 0; j < 8; ++j)
                    v[q][j] = (short)f2bf(src[(size_t)(q * 8 + j) * HW]);
        } else {
#pragma unroll
            for (int q = 0; q < 4; ++q)
#pragma unroll
                for (int j = 0; j < 8; ++j)
                    v[q][j] = 0;
        }
        uint32_t base_byte = (uint32_t)i * 64;
        uint32_t sw = ((uint32_t)(px >> 1) & 3u) << 4;
#pragma unroll
        for (int q = 0; q < 4; ++q)
            *(bf16x8*)((char*)lds + base_byte + (((uint32_t)q << 4) ^ sw)) = v[q];
    }
    __syncthreads();

    // ---- compute: wave = output row h0+wid, N=128 px, M=64 oc ----
    int wid  = tid >> 6;
    int lane = tid & 63;
    int llo  = lane & 15;
    int lhi  = lane >> 4;
    int h    = h0 + wid;

    f32x4 acc[4][8];
#pragma unroll
    for (int g = 0; g < 4; ++g)
#pragma unroll
        for (int nf = 0; nf < 8; ++nf) {
            acc[g][nf][0] = 0.f; acc[g][nf][1] = 0.f;
            acc[g][nf][2] = 0.f; acc[g][nf][3] = 0.f;
        }

#pragma unroll
    for (int tap = 0; tap < 9; ++tap) {
        int dy = tap / 3;
        int dx = tap % 3;
        bf16x8 Af[4];
#pragma unroll
        for (int g = 0; g < 4; ++g)
            Af[g] = *(const bf16x8*)(Wp + ((size_t)(tap * 4 + g) * 64 + lane) * 8);
        int rbase = (wid + dy) * PXW;
#pragma unroll
        for (int nf = 0; nf < 8; ++nf) {
            int px = nf * 16 + llo + dx;
            uint32_t byte = (uint32_t)(rbase + px) * 64u +
                            (((uint32_t)lhi << 4) ^ ((((uint32_t)px >> 1) & 3u) << 4));
            bf16x8 Bf = *(const bf16x8*)((const char*)lds + byte);
#pragma unroll
            for (int g = 0; g < 4; ++g)
                acc[g][nf] = __builtin_amdgcn_mfma_f32_16x16x32_bf16(Af[g], Bf, acc[g][nf], 0, 0, 0);
        }
    }

    // ---- store: C/D layout col=lane&15 (pixel), row=(lane>>4)*4+r (oc) ----
    float* obase = out + (size_t)b * COUT * HW + (size_t)h * W_;
#pragma unroll
    for (int g = 0; g < 4; ++g)
#pragma unroll
        for (int nf = 0; nf < 8; ++nf) {
            int x = nf * 16 + llo;
#pragma unroll
            for (int r = 0; r < 4; ++r) {
                int oc = g * 16 + lhi * 4 + r;
                obase[(size_t)oc * HW + x] = acc[g][nf][r];
            }
        }
}

// ---------------------------------------------------------------------------
// Fallback: naive fp32 direct conv (only if workspace is too small for Wp)
// ---------------------------------------------------------------------------
__global__ void conv_naive_kernel(const float* __restrict__ in,
                                  const float* __restrict__ wt,
                                  float* __restrict__ out) {
    int idx = blockIdx.x * blockDim.x + threadIdx.x;
    if (idx >= B_ * COUT * HW) return;
    int w  = idx & 127;
    int h  = (idx >> 7) & 127;
    int oc = (idx >> 14) & 63;
    int b  = idx >> 20;
    float s = 0.f;
    for (int c = 0; c < CIN; ++c)
        for (int ky = 0; ky < 3; ++ky) {
            int y = h + ky - 1;
            if ((unsigned)y >= (unsigned)H_) continue;
            for (int kx = 0; kx < 3; ++kx) {
                int x = w + kx - 1;
                if ((unsigned)x >= (unsigned)W_) continue;
                s += in[((size_t)(b * CIN + c) * H_ + y) * W_ + x] *
                     wt[(((size_t)oc * CIN + c) * 3 + ky) * 3 + kx];
            }
        }
    out[idx] = s;
}

extern "C" void kernel_launch(void* const* d_in, const int* in_sizes, int n_in,
                              void* d_out, int out_size, void* d_ws, size_t ws_size,
                              hipStream_t stream) {
    const float* in = (const float*)d_in[0];
    const float* wt = (const float*)d_in[1];
    float* out = (float*)d_out;

    size_t Wp_bytes = (size_t)COUT * CIN * 9 * 2;   // 36,864

    if (ws_size >= Wp_bytes) {
        ushort* Wp = (ushort*)d_ws;
        prep_w_kernel<<<(COUT * CIN * 9 + 255) / 256, 256, 0, stream>>>(wt, Wp);
        conv_fused_kernel<<<B_ * (H_ / T_), 256, 0, stream>>>(in, Wp, out);
    } else {
        int total = B_ * COUT * HW;
        conv_naive_kernel<<<(total + 255) / 256, 256, 0, stream>>>(in, wt, out);
    }
}